// Round 4
// baseline (80.642 us; speedup 1.0000x reference)
//
#include <hip/hip_runtime.h>
#include <hip/hip_bf16.h>
#include <stdint.h>

#define N_NODES 100000
#define DEG 16
#define IN_F 128
#define OUT_F 64
#define ALPHA 0.2f

typedef __attribute__((ext_vector_type(8))) short short8;
typedef __attribute__((ext_vector_type(4))) float f32x4;
typedef __attribute__((ext_vector_type(4))) int i32x4;
typedef __attribute__((ext_vector_type(4))) unsigned int u32x4;

static __device__ __forceinline__ unsigned int pack2bf(float lo, float hi) {
    // RTNE pair conversion; compiler emits v_cvt_pk_bf16_f32
    __hip_bfloat162 h = __float22bfloat162_rn(make_float2(lo, hi));
    unsigned int u; __builtin_memcpy(&u, &h, 4); return u;
}
static __device__ __forceinline__ unsigned short f2bf(float f) {
    __hip_bfloat16 h = __float2bfloat16(f);   // RTNE
    unsigned short u; __builtin_memcpy(&u, &h, 2); return u;
}

// Prep: w -> bf16 (all blocks), v1 = w^T a1w, v2 = w^T a2w (block 0).
// a1 = feat@a1w = x@(w^T a1w) = x@v1  -- exact algebraic refactor, f32 throughout.
__global__ __launch_bounds__(256) void prep_kernel(
    const float* __restrict__ w, const float* __restrict__ a1w,
    const float* __restrict__ a2w, unsigned short* __restrict__ wb,
    float* __restrict__ v1, float* __restrict__ v2)
{
    int idx = blockIdx.x * 256 + threadIdx.x;
    if (idx < OUT_F * IN_F) wb[idx] = f2bf(w[idx]);
    if (blockIdx.x == 0) {
        int t = threadIdx.x;
        int k = t & (IN_F - 1);
        const float* aw = (t < IN_F) ? a1w : a2w;
        float acc = 0.f;
        #pragma unroll
        for (int f = 0; f < OUT_F; ++f) acc += w[f * IN_F + k] * aw[f];
        if (t < IN_F) v1[k] = acc; else v2[k] = acc;
    }
}

// Kernel 1: feat = x @ w^T via bf16 MFMA (f32 accum); a1/a2 via f32 dots x.v1, x.v2.
// One 64-thread block = one wave = 32 nodes x 64 features (3125 blocks -> ~12/CU,
// smooth tail). All 16 x-loads hoisted (NT: zero reuse); w fragments re-read per ks
// (L1-hot). LDS bounce XOR-swizzled (col ^= g<<4) to kill the 8-way write conflict.
__global__ __launch_bounds__(64) void gat_feat_kernel(
    const float* __restrict__ x, const unsigned short* __restrict__ wb,
    const float* __restrict__ v1, const float* __restrict__ v2,
    const float* __restrict__ a1bp, const float* __restrict__ a2bp,
    unsigned short* __restrict__ featb, float* __restrict__ a1,
    float* __restrict__ a2)
{
    __shared__ __align__(16) unsigned short lds[32][64]; // 4 KB store-bounce tile
    const int lane = threadIdx.x & 63;
    const int r = lane & 15;   // A row / B col within 16-tile
    const int g = lane >> 4;   // k-group (8 contiguous k per group)
    const unsigned base = blockIdx.x * 32;   // N % 32 == 0: always full

    // hoist all x loads (16 x 16B, independent addresses -> max MLP; NT, no reuse)
    f32x4 xr[2][4][2];
    #pragma unroll
    for (int mt = 0; mt < 2; ++mt) {
        const float* xrow = x + (size_t)(base + mt * 16 + r) * IN_F + g * 8;
        #pragma unroll
        for (int ks = 0; ks < 4; ++ks) {
            xr[mt][ks][0] = __builtin_nontemporal_load((const f32x4*)(xrow + ks * 32));
            xr[mt][ks][1] = __builtin_nontemporal_load((const f32x4*)(xrow + ks * 32 + 4));
        }
    }

    f32x4 acc[2][4];
    #pragma unroll
    for (int mt = 0; mt < 2; ++mt)
        #pragma unroll
        for (int ft = 0; ft < 4; ++ft) acc[mt][ft] = (f32x4){0.f, 0.f, 0.f, 0.f};
    float p1[2] = {0.f, 0.f}, p2[2] = {0.f, 0.f};

    #pragma unroll
    for (int ks = 0; ks < 4; ++ks) {
        short8 bf[4];
        #pragma unroll
        for (int ft = 0; ft < 4; ++ft)
            bf[ft] = *(const short8*)(wb + (ft * 16 + r) * IN_F + ks * 32 + g * 8);
        const float* vp1 = v1 + ks * 32 + g * 8;
        const float* vp2 = v2 + ks * 32 + g * 8;
        f32x4 v10 = *(const f32x4*)(vp1), v11 = *(const f32x4*)(vp1 + 4);
        f32x4 v20 = *(const f32x4*)(vp2), v21 = *(const f32x4*)(vp2 + 4);
        #pragma unroll
        for (int mt = 0; mt < 2; ++mt) {
            f32x4 x0 = xr[mt][ks][0], x1 = xr[mt][ks][1];
            #pragma unroll
            for (int j = 0; j < 4; ++j) {
                p1[mt] += x0[j] * v10[j] + x1[j] * v11[j];
                p2[mt] += x0[j] * v20[j] + x1[j] * v21[j];
            }
            u32x4 au;
            au[0] = pack2bf(x0[0], x0[1]);
            au[1] = pack2bf(x0[2], x0[3]);
            au[2] = pack2bf(x1[0], x1[1]);
            au[3] = pack2bf(x1[2], x1[3]);
            short8 af; __builtin_memcpy(&af, &au, 16);
            #pragma unroll
            for (int ft = 0; ft < 4; ++ft)
                acc[mt][ft] = __builtin_amdgcn_mfma_f32_16x16x32_bf16(af, bf[ft], acc[mt][ft], 0, 0, 0);
        }
    }
    // C/D layout (HW-verified): col = lane&15 -> feature ft*16+r; row = g*4+reg -> node mt*16+g*4+reg

    // a1/a2: reduce partial dots over the 4 k-groups (lanes differing only in g)
    #pragma unroll
    for (int mt = 0; mt < 2; ++mt) {
        p1[mt] += __shfl_xor(p1[mt], 16, 64);
        p1[mt] += __shfl_xor(p1[mt], 32, 64);
        p2[mt] += __shfl_xor(p2[mt], 16, 64);
        p2[mt] += __shfl_xor(p2[mt], 32, 64);
    }
    if (lane < 16) {
        float b1 = a1bp[0], b2 = a2bp[0];
        #pragma unroll
        for (int mt = 0; mt < 2; ++mt) {
            a1[base + mt * 16 + lane] = p1[mt] + b1;
            a2[base + mt * 16 + lane] = p2[mt] + b2;
        }
    }

    // feat -> bf16 -> LDS (XOR-swizzled: phys col = col ^ (g<<4); row>>2 & 3 == g)
    #pragma unroll
    for (int mt = 0; mt < 2; ++mt)
        #pragma unroll
        for (int ft = 0; ft < 4; ++ft) {
            const int cp = (ft * 16 + r) ^ (g << 4);
            #pragma unroll
            for (int reg = 0; reg < 4; ++reg)
                lds[mt * 16 + g * 4 + reg][cp] = f2bf(acc[mt][ft][reg]);
        }
    // same-wave LDS RAW (single wave per block: no barrier needed)
    char* gdst = (char*)featb + (size_t)base * (OUT_F * 2);
    #pragma unroll
    for (int t = 0; t < 4; ++t) {
        const int row = t * 8 + (lane >> 3);
        const int cl  = (lane & 7) * 8;
        const int cp  = cl ^ (((row >> 2) & 3) << 4);
        i32x4 v = *(const i32x4*)(&lds[row][cp]);
        *(i32x4*)(gdst + (size_t)row * 128 + cl * 2) = v;   // == gdst + t*1024 + lane*16
    }
}

// Kernel 2: per-node scores + gather-aggregate. One wave = 4 nodes x 16 lanes.
// Lane within group: eh = (lane>>3)&1 (edge parity), fq = lane&7 (feature octet).
// Each gather is a dwordx4 (8 bf16 features); all 8 gathers in flight before consume;
// cross-half combine via shfl_xor(8). out/x/dst streams are nontemporal so featb
// stays L2-resident for the random gathers.
__global__ __launch_bounds__(256) void gat_agg_kernel(
    const int* __restrict__ dst, const unsigned short* __restrict__ featb,
    const float* __restrict__ a1, const float* __restrict__ a2,
    const float* __restrict__ bias, float* __restrict__ out)
{
    const int wid  = threadIdx.x >> 6;
    const int lane = threadIdx.x & 63;
    const int e0 = lane & 15;
    const int eh = (lane >> 3) & 1;
    const int fq = lane & 7;
    const int sb = lane & 48;                       // first lane of this node's group
    const int i = (blockIdx.x * 4 + wid) * 4 + (lane >> 4);   // N % 16 == 0: exact

    const int d = __builtin_nontemporal_load(dst + i * DEG + e0);

    // collect the 8 (2t+eh) dst rows and fire all gathers before touching scores
    u32x4 u[8];
    #pragma unroll
    for (int t = 0; t < 8; ++t) {
        const int de = __shfl(d, sb + 2 * t + eh, 64);
        u[t] = *(const u32x4*)(featb + (unsigned)de * OUT_F + fq * 8);
    }

    // scores while gathers are in flight
    const float z = a1[i] + a2[d];
    const float s = __expf(fmaxf(z, ALPHA * z));    // leaky_relu == max(z, 0.2z)
    float ssum = s;
    #pragma unroll
    for (int m = 1; m <= 8; m <<= 1) ssum += __shfl_xor(ssum, m, 64);
    float se[8];
    #pragma unroll
    for (int t = 0; t < 8; ++t) se[t] = __shfl(s, sb + 2 * t + eh, 64);

    float acc[8] = {0.f,0.f,0.f,0.f,0.f,0.f,0.f,0.f};
    #pragma unroll
    for (int t = 0; t < 8; ++t)
        #pragma unroll
        for (int w = 0; w < 4; ++w) {
            acc[2 * w]     += se[t] * __uint_as_float(u[t][w] << 16);
            acc[2 * w + 1] += se[t] * __uint_as_float(u[t][w] & 0xffff0000u);
        }
    #pragma unroll
    for (int j = 0; j < 8; ++j) acc[j] += __shfl_xor(acc[j], 8, 64);
    // every lane now has the full 8-feature sums for octet fq

    const float inv = 1.0f / ssum;
    const f32x4 bv = *(const f32x4*)(bias + fq * 8 + eh * 4);
    f32x4 o;
    #pragma unroll
    for (int j = 0; j < 4; ++j) {
        const float aj = eh ? acc[4 + j] : acc[j];   // static indices (no scratch)
        o[j] = aj * inv + bv[j];
    }
    __builtin_nontemporal_store(o, (f32x4*)(out + (unsigned)i * OUT_F + fq * 8 + eh * 4));
}

extern "C" void kernel_launch(void* const* d_in, const int* in_sizes, int n_in,
                              void* d_out, int out_size, void* d_ws, size_t ws_size,
                              hipStream_t stream) {
    (void)in_sizes; (void)n_in; (void)out_size; (void)ws_size;
    const float* x    = (const float*)d_in[0];
    const int*   edges= (const int*)d_in[1];   // [2, E] int32, row0=src, row1=dst
    const float* w    = (const float*)d_in[2];
    const float* a1w  = (const float*)d_in[3];
    const float* a1b  = (const float*)d_in[4];
    const float* a2w  = (const float*)d_in[5];
    const float* a2b  = (const float*)d_in[6];
    const float* bias = (const float*)d_in[7];
    float* out = (float*)d_out;

    // ws layout (all 16B-aligned): featb | a1 | a2 | v1 | v2 | wb
    unsigned short* featb = (unsigned short*)d_ws;                       // N*64 bf16 = 12.8 MB
    float* a1 = (float*)((char*)d_ws + (size_t)N_NODES * OUT_F * 2);
    float* a2 = a1 + N_NODES;
    float* v1 = a2 + N_NODES;
    float* v2 = v1 + IN_F;
    unsigned short* wb = (unsigned short*)(v2 + IN_F);

    const int* dst = edges + (size_t)N_NODES * DEG; // edges[1]

    prep_kernel<<<dim3((OUT_F * IN_F + 255) / 256), dim3(256), 0, stream>>>(
        w, a1w, a2w, wb, v1, v2);
    gat_feat_kernel<<<dim3(N_NODES / 32), dim3(64), 0, stream>>>(
        x, wb, v1, v2, a1b, a2b, featb, a1, a2);
    gat_agg_kernel<<<dim3(N_NODES / 16), dim3(256), 0, stream>>>(
        dst, featb, a1, a2, bias, out);
}

// Round 5
// 65.646 us; speedup vs baseline: 1.2284x; 1.2284x over previous
//
#include <hip/hip_runtime.h>
#include <hip/hip_bf16.h>
#include <stdint.h>

#define N_NODES 100000
#define DEG 16
#define IN_F 128
#define OUT_F 64
#define ALPHA 0.2f

typedef __attribute__((ext_vector_type(8))) short short8;
typedef __attribute__((ext_vector_type(4))) float f32x4;
typedef __attribute__((ext_vector_type(4))) int i32x4;
typedef __attribute__((ext_vector_type(4))) unsigned int u32x4;
typedef __attribute__((ext_vector_type(2))) unsigned int u32x2;

static __device__ __forceinline__ unsigned int pack2bf(float lo, float hi) {
    // RTNE pair conversion; compiler emits v_cvt_pk_bf16_f32
    __hip_bfloat162 h = __float22bfloat162_rn(make_float2(lo, hi));
    unsigned int u; __builtin_memcpy(&u, &h, 4); return u;
}
static __device__ __forceinline__ unsigned short f2bf(float f) {
    __hip_bfloat16 h = __float2bfloat16(f);   // RTNE
    unsigned short u; __builtin_memcpy(&u, &h, 2); return u;
}

// Prep: w -> bf16 (all blocks); v1 = w^T a1w (block 0).
// a1 = feat@a1w = x@(w^T a1w) = x@v1  -- exact algebraic refactor, f32 throughout.
// (a2 is reconstructed in the agg kernel from the gathered feat rows: a2[d] = feat[d].a2w,
//  so no v2 / a2 array / per-edge a2 gather exists at all.)
__global__ __launch_bounds__(256) void prep_kernel(
    const float* __restrict__ w, const float* __restrict__ a1w,
    unsigned short* __restrict__ wb, float* __restrict__ v1)
{
    int idx = blockIdx.x * 256 + threadIdx.x;
    if (idx < OUT_F * IN_F) wb[idx] = f2bf(w[idx]);
    if (blockIdx.x == 0 && threadIdx.x < IN_F) {
        int k = threadIdx.x;
        float acc = 0.f;
        #pragma unroll
        for (int f = 0; f < OUT_F; ++f) acc += w[f * IN_F + k] * a1w[f];
        v1[k] = acc;
    }
}

// Kernel 1: feat = x @ w^T via bf16 MFMA (f32 accum); a1 via f32 dot x.v1.
// One 64-thread block = one wave = 32 nodes x 64 features. All 16 x-loads hoisted
// (NT: zero reuse); w fragments re-read per ks (L1-hot). LDS bounce XOR-swizzled.
__global__ __launch_bounds__(64) void gat_feat_kernel(
    const float* __restrict__ x, const unsigned short* __restrict__ wb,
    const float* __restrict__ v1, const float* __restrict__ a1bp,
    unsigned short* __restrict__ featb, float* __restrict__ a1)
{
    __shared__ __align__(16) unsigned short lds[32][64]; // 4 KB store-bounce tile
    const int lane = threadIdx.x & 63;
    const int r = lane & 15;   // A row / B col within 16-tile
    const int g = lane >> 4;   // k-group (8 contiguous k per group)
    const unsigned base = blockIdx.x * 32;   // N % 32 == 0: always full

    // hoist all x loads (16 x 16B, independent addresses -> max MLP; NT, no reuse)
    f32x4 xr[2][4][2];
    #pragma unroll
    for (int mt = 0; mt < 2; ++mt) {
        const float* xrow = x + (size_t)(base + mt * 16 + r) * IN_F + g * 8;
        #pragma unroll
        for (int ks = 0; ks < 4; ++ks) {
            xr[mt][ks][0] = __builtin_nontemporal_load((const f32x4*)(xrow + ks * 32));
            xr[mt][ks][1] = __builtin_nontemporal_load((const f32x4*)(xrow + ks * 32 + 4));
        }
    }

    f32x4 acc[2][4];
    #pragma unroll
    for (int mt = 0; mt < 2; ++mt)
        #pragma unroll
        for (int ft = 0; ft < 4; ++ft) acc[mt][ft] = (f32x4){0.f, 0.f, 0.f, 0.f};
    float p1[2] = {0.f, 0.f};

    #pragma unroll
    for (int ks = 0; ks < 4; ++ks) {
        short8 bf[4];
        #pragma unroll
        for (int ft = 0; ft < 4; ++ft)
            bf[ft] = *(const short8*)(wb + (ft * 16 + r) * IN_F + ks * 32 + g * 8);
        const float* vp1 = v1 + ks * 32 + g * 8;
        f32x4 v10 = *(const f32x4*)(vp1), v11 = *(const f32x4*)(vp1 + 4);
        #pragma unroll
        for (int mt = 0; mt < 2; ++mt) {
            f32x4 x0 = xr[mt][ks][0], x1 = xr[mt][ks][1];
            #pragma unroll
            for (int j = 0; j < 4; ++j)
                p1[mt] += x0[j] * v10[j] + x1[j] * v11[j];
            u32x4 au;
            au[0] = pack2bf(x0[0], x0[1]);
            au[1] = pack2bf(x0[2], x0[3]);
            au[2] = pack2bf(x1[0], x1[1]);
            au[3] = pack2bf(x1[2], x1[3]);
            short8 af; __builtin_memcpy(&af, &au, 16);
            #pragma unroll
            for (int ft = 0; ft < 4; ++ft)
                acc[mt][ft] = __builtin_amdgcn_mfma_f32_16x16x32_bf16(af, bf[ft], acc[mt][ft], 0, 0, 0);
        }
    }
    // C/D layout (HW-verified): col = lane&15 -> feature ft*16+r; row = g*4+reg -> node mt*16+g*4+reg

    // a1: reduce partial dots over the 4 k-groups (lanes differing only in g)
    #pragma unroll
    for (int mt = 0; mt < 2; ++mt) {
        p1[mt] += __shfl_xor(p1[mt], 16, 64);
        p1[mt] += __shfl_xor(p1[mt], 32, 64);
    }
    if (lane < 16) {
        float b1 = a1bp[0];
        #pragma unroll
        for (int mt = 0; mt < 2; ++mt)
            a1[base + mt * 16 + lane] = p1[mt] + b1;
    }

    // feat -> bf16 -> LDS (XOR-swizzled: phys col = col ^ (g<<4))
    #pragma unroll
    for (int mt = 0; mt < 2; ++mt)
        #pragma unroll
        for (int ft = 0; ft < 4; ++ft) {
            const int cp = (ft * 16 + r) ^ (g << 4);
            #pragma unroll
            for (int reg = 0; reg < 4; ++reg)
                lds[mt * 16 + g * 4 + reg][cp] = f2bf(acc[mt][ft][reg]);
        }
    // same-wave LDS RAW (single wave per block: no barrier needed)
    char* gdst = (char*)featb + (size_t)base * (OUT_F * 2);
    #pragma unroll
    for (int t = 0; t < 4; ++t) {
        const int row = t * 8 + (lane >> 3);
        const int cl  = (lane & 7) * 8;
        const int cp  = cl ^ (((row >> 2) & 3) << 4);
        i32x4 v = *(const i32x4*)(&lds[row][cp]);
        *(i32x4*)(gdst + (size_t)row * 128 + cl * 2) = v;   // == gdst + t*1024 + lane*16
    }
}

#define BFLO(w_) __uint_as_float((w_) << 16)
#define BFHI(w_) __uint_as_float((w_) & 0xffff0000u)

// Kernel 2: per-node scores + gather-aggregate. One wave = 4 nodes x 16 lanes.
// Lane e0 = lane&15 owns edge e0 (for dst) and feature-quad e0 (for gathers).
// For each edge t the 16-lane group cooperatively gathers row dst_t (16 x 8B = one
// 128B line, ONE L2 request), then reconstructs a2[dst_t] = feat[dst_t].a2w from the
// gathered chunks (4 FMA + 4 shfl_xor) -- eliminating the 1.6M random a2 gathers that
// made R2/R4 request-rate-bound. All 16 gathers are NAMED registers (no arrays ->
// no alloca-to-LDS spill, the R4 regression) and issued before any consumption.
__global__ __launch_bounds__(256) void gat_agg_kernel(
    const int* __restrict__ dst, const unsigned short* __restrict__ featb,
    const float* __restrict__ a1, const float* __restrict__ a2w,
    const float* __restrict__ a2bp, const float* __restrict__ bias,
    float* __restrict__ out)
{
    const int wid  = threadIdx.x >> 6;
    const int lane = threadIdx.x & 63;
    const int e0 = lane & 15;
    const int sb = lane & 48;                       // first lane of this node's group
    const int i = (blockIdx.x * 4 + wid) * 4 + (lane >> 4);   // N % 16 == 0: exact

    const int d = dst[i * DEG + e0];

    // fire all 16 row-gathers (chunk e0 of edge t's row) before touching anything else
#define GATH(t) \
    const int de##t = __shfl(d, sb + (t), 64); \
    const u32x2 u##t = *(const u32x2*)(featb + (unsigned)de##t * OUT_F + e0 * 4);
    GATH(0)  GATH(1)  GATH(2)  GATH(3)
    GATH(4)  GATH(5)  GATH(6)  GATH(7)
    GATH(8)  GATH(9)  GATH(10) GATH(11)
    GATH(12) GATH(13) GATH(14) GATH(15)
#undef GATH

    const float a1i = a1[i] + a2bp[0];              // fold a2 bias into the constant
    const f32x4 aw = *(const f32x4*)(a2w + e0 * 4);
    const f32x4 bv = *(const f32x4*)(bias + e0 * 4);

    float acc0 = 0.f, acc1 = 0.f, acc2 = 0.f, acc3 = 0.f, ssum = 0.f;
#define EDGE(t) { \
    const float f0 = BFLO(u##t[0]), f1 = BFHI(u##t[0]); \
    const float f2 = BFLO(u##t[1]), f3 = BFHI(u##t[1]); \
    float p = f0 * aw[0] + f1 * aw[1] + f2 * aw[2] + f3 * aw[3]; \
    p += __shfl_xor(p, 1, 64); p += __shfl_xor(p, 2, 64); \
    p += __shfl_xor(p, 4, 64); p += __shfl_xor(p, 8, 64); \
    const float z = a1i + p; \
    const float s = __expf(fmaxf(z, ALPHA * z)); \
    ssum += s; \
    acc0 += s * f0; acc1 += s * f1; acc2 += s * f2; acc3 += s * f3; }
    EDGE(0)  EDGE(1)  EDGE(2)  EDGE(3)
    EDGE(4)  EDGE(5)  EDGE(6)  EDGE(7)
    EDGE(8)  EDGE(9)  EDGE(10) EDGE(11)
    EDGE(12) EDGE(13) EDGE(14) EDGE(15)
#undef EDGE

    const float inv = 1.0f / ssum;
    f32x4 o;
    o[0] = acc0 * inv + bv[0];
    o[1] = acc1 * inv + bv[1];
    o[2] = acc2 * inv + bv[2];
    o[3] = acc3 * inv + bv[3];
    __builtin_nontemporal_store(o, (f32x4*)(out + (unsigned)i * OUT_F + e0 * 4));
}

extern "C" void kernel_launch(void* const* d_in, const int* in_sizes, int n_in,
                              void* d_out, int out_size, void* d_ws, size_t ws_size,
                              hipStream_t stream) {
    (void)in_sizes; (void)n_in; (void)out_size; (void)ws_size;
    const float* x    = (const float*)d_in[0];
    const int*   edges= (const int*)d_in[1];   // [2, E] int32, row0=src, row1=dst
    const float* w    = (const float*)d_in[2];
    const float* a1w  = (const float*)d_in[3];
    const float* a1b  = (const float*)d_in[4];
    const float* a2w  = (const float*)d_in[5];
    const float* a2b  = (const float*)d_in[6];
    const float* bias = (const float*)d_in[7];
    float* out = (float*)d_out;

    // ws layout (all 16B-aligned): featb | a1 | v1 | wb
    unsigned short* featb = (unsigned short*)d_ws;                       // N*64 bf16 = 12.8 MB
    float* a1 = (float*)((char*)d_ws + (size_t)N_NODES * OUT_F * 2);
    float* v1 = a1 + N_NODES;
    unsigned short* wb = (unsigned short*)(v1 + IN_F);

    const int* dst = edges + (size_t)N_NODES * DEG; // edges[1]

    prep_kernel<<<dim3((OUT_F * IN_F + 255) / 256), dim3(256), 0, stream>>>(
        w, a1w, wb, v1);
    gat_feat_kernel<<<dim3(N_NODES / 32), dim3(64), 0, stream>>>(
        x, wb, v1, a1b, featb, a1);
    gat_agg_kernel<<<dim3(N_NODES / 16), dim3(256), 0, stream>>>(
        dst, featb, a1, a2w, a2b, bias, out);
}